// Round 1
// baseline (235.172 us; speedup 1.0000x reference)
//
#include <hip/hip_runtime.h>

// Problem constants (B=16, C=128, H=W=64, N=4096, M=256, K=9, OUT=128)
#define NB   16
#define NC   128
#define NN   4096
#define NM   256
#define NK   9
#define NO   128

#define DELTA 0.03f   // covers split-bf16 + fp32-accum key error (<=~1e-3) with big margin

typedef __attribute__((ext_vector_type(8))) short bf16x8;
typedef __attribute__((ext_vector_type(4))) float f32x4;

__device__ __constant__ int d_grid16[16] = {0,4,8,13,17,21,25,29,34,38,42,46,50,55,59,63};

__device__ inline unsigned short bf16_rne(float v) {
    unsigned u = __float_as_uint(v);
    return (unsigned short)((u + 0x7FFFu + ((u >> 16) & 1u)) >> 16);
}

// ---------------------------------------------------------------------------
// K_PREP: unchanged except reduction loops unrolled 16 (loads independent,
// add chain order preserved -> still np-bit-exact).
__global__ __launch_bounds__(256) void k_prep(const float* __restrict__ x,
                                              const float* __restrict__ w,
                                              float* __restrict__ xsT,
                                              unsigned short* __restrict__ xsTh,
                                              unsigned short* __restrict__ xsTl,
                                              unsigned short* __restrict__ Wth,
                                              unsigned short* __restrict__ Wtl,
                                              float* __restrict__ n2g,
                                              float* __restrict__ m2) {
    __shared__ float tile[16 * 260];
    int bx = blockIdx.x, t = threadIdx.x;
    if (bx < 128) {
        int b = bx >> 3, c0 = (bx & 7) * 16;
        int m = t;
        int pix = d_grid16[m >> 4] * 64 + d_grid16[m & 15];
        #pragma unroll
        for (int cc = 0; cc < 16; ++cc)
            tile[cc * 260 + m] = x[((size_t)b * NC + c0 + cc) * NN + pix];
        __syncthreads();
        #pragma unroll
        for (int e = 0; e < 4; ++e) {
            float fv[4];
            fv[0] = tile[(4 * e + 0) * 260 + m];
            fv[1] = tile[(4 * e + 1) * 260 + m];
            fv[2] = tile[(4 * e + 2) * 260 + m];
            fv[3] = tile[(4 * e + 3) * 260 + m];
            size_t base = ((size_t)b * NM + m) * NC + c0 + 4 * e;
            *(float4*)&xsT[base] = make_float4(fv[0], fv[1], fv[2], fv[3]);
            unsigned short h4[4], l4[4];
            #pragma unroll
            for (int e2 = 0; e2 < 4; ++e2) {
                unsigned short h = bf16_rne(fv[e2]);
                h4[e2] = h;
                l4[e2] = bf16_rne(fv[e2] - __uint_as_float(((unsigned)h) << 16));
            }
            *(ushort4*)&xsTh[base] = make_ushort4(h4[0], h4[1], h4[2], h4[3]);
            *(ushort4*)&xsTl[base] = make_ushort4(l4[0], l4[1], l4[2], l4[3]);
        }
    } else if (bx < 704) {
        int f = (bx - 128) * 256 + t;               // < 147456 = 1152*128
        int ko = f >> 7, c = f & 127;
        int o = ko & 127, k = ko >> 7;
        float v = w[(size_t)o * 1152 + c * 9 + k];
        unsigned short h = bf16_rne(v);
        Wth[f] = h;
        Wtl[f] = bf16_rne(v - __uint_as_float(((unsigned)h) << 16));
    } else if (bx < 960) {
        #pragma clang fp contract(off)
        int i = bx - 704;                           // 256 blocks: b x 16 n-chunks
        int b = i >> 4, n = (i & 15) * 256 + t;
        const float* p = x + (size_t)b * NC * NN + n;
        float a = 0.f;
        #pragma unroll 16
        for (int c = 0; c < NC; ++c) { float v = p[(size_t)c * NN]; a = __fadd_rn(a, __fmul_rn(v, v)); }
        n2g[(size_t)b * NN + n] = a;
    } else {
        #pragma clang fp contract(off)
        int b = bx - 960;                           // 16 blocks: t = m
        int pix = d_grid16[t >> 4] * 64 + d_grid16[t & 15];
        const float* p = x + (size_t)b * NC * NN + pix;
        float a = 0.f;
        #pragma unroll 16
        for (int c = 0; c < NC; ++c) { float v = p[(size_t)c * NN]; a = __fadd_rn(a, __fmul_rn(v, v)); }
        m2[b * NM + t] = a;
    }
}

// ---------------------------------------------------------------------------
// K_G (MFMA): G[b][m][k][o] = sum_c xs[m][c] * W[k,o][c], split-bf16 3-term.
__global__ __launch_bounds__(256) void k_g(const unsigned short* __restrict__ xsTh,
                                           const unsigned short* __restrict__ xsTl,
                                           const unsigned short* __restrict__ Wth,
                                           const unsigned short* __restrict__ Wtl,
                                           float* __restrict__ G) {
    int id = blockIdx.x;
    int b = id & 15, r = id >> 4;                   // r < 36
    int kk = r % 9, mt = r / 9;
    int t = threadIdx.x;
    int w = t >> 6, lane = t & 63;
    int lr = lane & 15, quad = lane >> 4;
    int m = b * NM + mt * 64 + w * 16 + lr;
    const unsigned short* aph = xsTh + (size_t)m * NC;
    const unsigned short* apl = xsTl + (size_t)m * NC;
    f32x4 acc[8];
    #pragma unroll
    for (int j = 0; j < 8; ++j) acc[j] = (f32x4){0.f, 0.f, 0.f, 0.f};
    #pragma unroll
    for (int kb = 0; kb < 4; ++kb) {
        int co = kb * 32 + quad * 8;
        bf16x8 Ah = *(const bf16x8*)&aph[co];
        bf16x8 Al = *(const bf16x8*)&apl[co];
        #pragma unroll
        for (int j = 0; j < 8; ++j) {
            size_t wrow = ((size_t)kk * 128 + 16 * j + lr) * NC + co;
            bf16x8 Bh = *(const bf16x8*)&Wth[wrow];
            bf16x8 Bl = *(const bf16x8*)&Wtl[wrow];
            acc[j] = __builtin_amdgcn_mfma_f32_16x16x32_bf16(Ah, Bh, acc[j], 0, 0, 0);
            acc[j] = __builtin_amdgcn_mfma_f32_16x16x32_bf16(Al, Bh, acc[j], 0, 0, 0);
            acc[j] = __builtin_amdgcn_mfma_f32_16x16x32_bf16(Ah, Bl, acc[j], 0, 0, 0);
        }
    }
    int mrow = b * NM + mt * 64 + w * 16 + quad * 4;
    #pragma unroll
    for (int j = 0; j < 8; ++j)
        #pragma unroll
        for (int r2 = 0; r2 < 4; ++r2)
            G[((size_t)(mrow + r2)) * 1152 + kk * 128 + 16 * j + lr] = acc[j][r2];
}

// ---------------------------------------------------------------------------
// K_SELREF v2: swapped-operand MFMA (A=samples, B=tokens) so that each lane
// holds ALL 16 of its keys for ONE token (token = lane&15) in registers.
// Selection = per-lane Batcher sort-16 network + 2-round quad butterfly +
// small cross-wave LDS merge. No keysl buffer, fewer barriers, less LDS.
// Grid 4096 = 16 b (XCD-friendly low bits) x 256 token-tiles of 16 tokens.
// Approx keys are BIT-IDENTICAL to v1 (same dot order, same term order).
__global__ __launch_bounds__(256, 4) void k_selref(const float* __restrict__ x,
                                                   const unsigned short* __restrict__ xsTh,
                                                   const unsigned short* __restrict__ xsTl,
                                                   const float* __restrict__ xsT,
                                                   const float* __restrict__ m2,
                                                   const float* __restrict__ n2g,
                                                   int* __restrict__ idx) {
    #pragma clang fp contract(off)
    __shared__ __align__(16) float x1l[16 * 132];            // 8448 B  [tok][c]
    __shared__ __align__(16) unsigned short xhp[16 * 136];   // 4352 B  bf16-hi plane
    __shared__ __align__(16) unsigned short xlp[16 * 136];   // 4352 B  bf16-lo plane
    __shared__ __align__(16) unsigned wl[4 * 16 * 9];        // 2304 B  [wave][tok][9]; aliased by pairs
    __shared__ float m2l[256];
    __shared__ float n2l[16];
    __shared__ int cntl[16];
    __shared__ unsigned short candl[16 * 16];
    unsigned long long* pairs = (unsigned long long*)wl;     // 16*17*8 = 2176 <= 2304

    int b = blockIdx.x & 15, n0 = (blockIdx.x >> 4) * 16;
    int t = threadIdx.x;
    int w = t >> 6, lane = t & 63;
    int lr = lane & 15, quad = lane >> 4;

    m2l[t] = m2[b * NM + t];
    if (t < 16) { n2l[t] = n2g[(size_t)b * NN + n0 + t]; cntl[t] = 0; }

    // ---- stage x1l [tok][c] (transpose during write) ----
    #pragma unroll
    for (int it = 0; it < 2; ++it) {
        int f = it * 256 + t;                   // < 512
        int c = f >> 2, nn4 = (f & 3) * 4;
        float4 v = *(const float4*)&x[((size_t)b * NC + c) * NN + n0 + nn4];
        x1l[(nn4 + 0) * 132 + c] = v.x;
        x1l[(nn4 + 1) * 132 + c] = v.y;
        x1l[(nn4 + 2) * 132 + c] = v.z;
        x1l[(nn4 + 3) * 132 + c] = v.w;
    }
    __syncthreads();

    // ---- cooperative split-bf16 conversion of token planes (8 elems/thread) ----
    {
        int tok = t >> 4, c0 = (t & 15) * 8;
        float vf[8];
        *(float4*)&vf[0] = *(const float4*)&x1l[tok * 132 + c0];
        *(float4*)&vf[4] = *(const float4*)&x1l[tok * 132 + c0 + 4];
        unsigned short h8[8], l8[8];
        #pragma unroll
        for (int e = 0; e < 8; ++e) {
            unsigned short h = bf16_rne(vf[e]);
            h8[e] = h;
            l8[e] = bf16_rne(vf[e] - __uint_as_float(((unsigned)h) << 16));
        }
        *(ushort4*)&xhp[tok * 136 + c0]     = make_ushort4(h8[0], h8[1], h8[2], h8[3]);
        *(ushort4*)&xhp[tok * 136 + c0 + 4] = make_ushort4(h8[4], h8[5], h8[6], h8[7]);
        *(ushort4*)&xlp[tok * 136 + c0]     = make_ushort4(l8[0], l8[1], l8[2], l8[3]);
        *(ushort4*)&xlp[tok * 136 + c0 + 4] = make_ushort4(l8[4], l8[5], l8[6], l8[7]);
    }
    __syncthreads();

    // ---- MFMA: A = samples (global planes), B = tokens (LDS planes) ----
    // D[row=m_local][col=token]; per-acc term order (sHtH, sHtL, sLtH) ==
    // v1's (tHsH, tLsH, tHsL): bit-identical keys.
    f32x4 acc[4];
    #pragma unroll
    for (int j = 0; j < 4; ++j) acc[j] = (f32x4){0.f, 0.f, 0.f, 0.f};
    int mbase = w * 64;
    #pragma unroll
    for (int kb = 0; kb < 4; ++kb) {
        bf16x8 Bh = *(const bf16x8*)&xhp[lr * 136 + kb * 32 + quad * 8];
        bf16x8 Bl = *(const bf16x8*)&xlp[lr * 136 + kb * 32 + quad * 8];
        #pragma unroll
        for (int j = 0; j < 4; ++j) {
            size_t arow = ((size_t)b * NM + mbase + 16 * j + lr) * NC + kb * 32 + quad * 8;
            bf16x8 Ah = *(const bf16x8*)&xsTh[arow];
            bf16x8 Al = *(const bf16x8*)&xsTl[arow];
            acc[j] = __builtin_amdgcn_mfma_f32_16x16x32_bf16(Ah, Bh, acc[j], 0, 0, 0);
            acc[j] = __builtin_amdgcn_mfma_f32_16x16x32_bf16(Ah, Bl, acc[j], 0, 0, 0);
            acc[j] = __builtin_amdgcn_mfma_f32_16x16x32_bf16(Al, Bh, acc[j], 0, 0, 0);
        }
    }

    // ---- per-lane keys (16, register-resident) -> Batcher sort-16 ----
    unsigned s16[16];
    #pragma unroll
    for (int j = 0; j < 4; ++j)
        #pragma unroll
        for (int r = 0; r < 4; ++r) {
            int m = mbase + 16 * j + quad * 4 + r;
            float key = fmaf(-2.f, acc[j][r], m2l[m]);
            unsigned u = __float_as_uint(key);
            u = (u & 0x80000000u) ? ~u : (u | 0x80000000u);
            s16[j * 4 + r] = u;
        }
    #define CE(i,jx) { unsigned a_ = s16[i], b_ = s16[jx]; s16[i] = min(a_, b_); s16[jx] = max(a_, b_); }
    // sort8 [0..7]
    CE(0,1) CE(2,3) CE(0,2) CE(1,3) CE(1,2)
    CE(4,5) CE(6,7) CE(4,6) CE(5,7) CE(5,6)
    CE(0,4) CE(2,6) CE(2,4) CE(1,5) CE(3,7) CE(3,5) CE(1,2) CE(3,4) CE(5,6)
    // sort8 [8..15]
    CE(8,9) CE(10,11) CE(8,10) CE(9,11) CE(9,10)
    CE(12,13) CE(14,15) CE(12,14) CE(13,15) CE(13,14)
    CE(8,12) CE(10,14) CE(10,12) CE(9,13) CE(11,15) CE(11,13) CE(9,10) CE(11,12) CE(13,14)
    // odd-even merge 8+8
    CE(0,8) CE(4,12) CE(4,8) CE(2,10) CE(6,14) CE(6,10) CE(2,4) CE(6,8) CE(10,12)
    CE(1,9) CE(5,13) CE(5,9) CE(3,11) CE(7,15) CE(7,11) CE(3,5) CE(7,9) CE(11,13)
    CE(1,2) CE(3,4) CE(5,6) CE(7,8) CE(9,10) CE(11,12) CE(13,14)
    #undef CE

    unsigned bk[9];
    #pragma unroll
    for (int jj = 0; jj < 9; ++jj) bk[jj] = s16[jj];

    // ---- butterfly merge across the 4 quads (token lr lives in lanes lr+16q) ----
    #pragma unroll
    for (int d = 16; d <= 32; d <<= 1) {
        unsigned pv[9];
        #pragma unroll
        for (int jj = 0; jj < 9; ++jj) pv[jj] = (unsigned)__shfl_xor((int)bk[jj], d, 64);
        #pragma unroll
        for (int jj = 0; jj < 9; ++jj) {
            unsigned v = pv[jj];
            if (v >= bk[8]) break;
            #pragma unroll
            for (int kk = 0; kk < 9; ++kk) {
                unsigned mn = min(v, bk[kk]);
                v = max(v, bk[kk]);
                bk[kk] = mn;
            }
        }
    }

    // ---- cross-wave merge via tiny LDS lists ----
    if (quad == 0) {
        #pragma unroll
        for (int jj = 0; jj < 9; ++jj) wl[(w * 16 + lr) * 9 + jj] = bk[jj];
    }
    __syncthreads();
    #pragma unroll
    for (int ww = 1; ww < 4; ++ww) {
        int wsrc = (w + ww) & 3;
        const unsigned* src = &wl[(wsrc * 16 + lr) * 9];
        for (int jj = 0; jj < 9; ++jj) {
            unsigned v = src[jj];
            if (v >= bk[8]) break;
            #pragma unroll
            for (int kk = 0; kk < 9; ++kk) {
                unsigned mn = min(v, bk[kk]);
                v = max(v, bk[kk]);
                bk[kk] = mn;
            }
        }
    }

    // ---- threshold + candidate scan (keys recomputed from acc: same bits) ----
    unsigned u9 = bk[8];
    unsigned ku = (u9 & 0x80000000u) ? (u9 & 0x7FFFFFFFu) : ~u9;
    float thf = __uint_as_float(ku) + DELTA;
    unsigned tu = __float_as_uint(thf);
    tu = (tu & 0x80000000u) ? ~tu : (tu | 0x80000000u);
    #pragma unroll
    for (int j = 0; j < 4; ++j)
        #pragma unroll
        for (int r = 0; r < 4; ++r) {
            int m = mbase + 16 * j + quad * 4 + r;
            float key = fmaf(-2.f, acc[j][r], m2l[m]);
            unsigned u = __float_as_uint(key);
            u = (u & 0x80000000u) ? ~u : (u | 0x80000000u);
            if (u <= tu) {
                int pos = atomicAdd(&cntl[lr], 1);
                if (pos < 16) candl[lr * 16 + pos] = (unsigned short)m;
            }
        }
    __syncthreads();
    if (t < 16) {
        int c = min(cntl[t], 16);
        for (int s = c; s < 16; ++s) candl[t * 16 + s] = 0xFFFFu;
    }
    __syncthreads();

    // ---- ref: np-bit-exact re-rank (16 tokens x 16 lanes x 1 slot) ----
    {
        int tok = t >> 4, q = t & 15;
        float n2 = n2l[tok];
        int m = candl[tok * 16 + q];
        unsigned long long p = ~0ull;
        if (m != 0xFFFF) {
            const float* xt = xsT + ((size_t)b * NM + m) * NC;
            float dot = 0.f;
            for (int c4 = 0; c4 < 32; ++c4) {   // sequential in-order: np order
                float4 xv = *(const float4*)&x1l[tok * 132 + 4 * c4];
                float4 sv = *(const float4*)&xt[4 * c4];
                dot = __fadd_rn(dot, __fmul_rn(xv.x, sv.x));
                dot = __fadd_rn(dot, __fmul_rn(xv.y, sv.y));
                dot = __fadd_rn(dot, __fmul_rn(xv.z, sv.z));
                dot = __fadd_rn(dot, __fmul_rn(xv.w, sv.w));
            }
            float key = __fsub_rn(__fadd_rn(n2, m2l[m]), __fmul_rn(2.f, dot));
            unsigned u = __float_as_uint(key);
            u = (u & 0x80000000u) ? ~u : (u | 0x80000000u);
            p = ((unsigned long long)u << 32) | (unsigned)m;
        }
        pairs[tok * 17 + q] = p;               // pairs aliases wl: 2 barriers since last read
        __syncthreads();
        unsigned long long pl[16];
        #pragma unroll
        for (int l2 = 0; l2 < 16; ++l2) pl[l2] = pairs[tok * 17 + l2];
        if (m != 0xFFFF) {
            int rank = 0;
            #pragma unroll
            for (int l2 = 0; l2 < 16; ++l2) rank += (pl[l2] < p);
            if (rank < 9) idx[(size_t)(b * NN + n0 + tok) * NK + rank] = m;
        }
    }
}

// ---------------------------------------------------------------------------
// K_OUT: out[b][o][n] = bias[o] + sum_k G[b][idx[b,n,k]][k][o]
__global__ __launch_bounds__(256) void k_out(const float* __restrict__ G,
                                             const int* __restrict__ idx,
                                             const float* __restrict__ bias,
                                             float* __restrict__ out) {
    __shared__ float S[64 * 129];
    __shared__ int   idxl[576];
    __shared__ float biasl[128];
    int b = blockIdx.x & 15, n0 = (blockIdx.x >> 4) * 64;
    int t = threadIdx.x;
    if (t < 128) biasl[t] = bias[t];
    for (int f = t; f < 576; f += 256) idxl[f] = idx[(size_t)(b * NN + n0) * NK + f];
    __syncthreads();
    int o = t & 127, half = t >> 7;
    for (int p = 0; p < 32; ++p) {
        int n = p * 2 + half;
        float a = biasl[o];
        #pragma unroll
        for (int k = 0; k < 9; ++k) {
            int m = idxl[n * 9 + k];
            a += G[(((size_t)(b * NM + m)) * NK + k) * 128 + o];
        }
        S[n * 129 + o] = a;
    }
    __syncthreads();
    int nn = t & 63, ob = t >> 6;
    for (int p = 0; p < 32; ++p) {
        int o2 = p * 4 + ob;
        out[((size_t)(b * NO + o2)) * NN + n0 + nn] = S[nn * 129 + o2];
    }
}

// ---------------------------------------------------------------------------
extern "C" void kernel_launch(void* const* d_in, const int* in_sizes, int n_in,
                              void* d_out, int out_size, void* d_ws, size_t ws_size,
                              hipStream_t stream) {
    const float* x    = (const float*)d_in[0];   // (16,128,64,64)
    const float* w    = (const float*)d_in[1];   // (128,128,9)
    const float* bias = (const float*)d_in[2];   // (128,)
    float* out = (float*)d_out;

    float* ws   = (float*)d_ws;
    float* m2   = ws;                            // 4096
    float* n2g  = ws + 4096;                     // 65536
    float* xsT  = ws + 69632;                    // 524288
    float* G    = ws + 593920;                   // 4718592
    int*   idx  = (int*)(ws + 5312512);          // 589824
    unsigned short* xsTh = (unsigned short*)(ws + 5902336);  // 524288 u16
    unsigned short* xsTl = (unsigned short*)(ws + 6164480);  // 524288 u16
    unsigned short* Wth  = (unsigned short*)(ws + 6426624);  // 147456 u16
    unsigned short* Wtl  = (unsigned short*)(ws + 6500352);  // 147456 u16

    k_prep  <<<dim3(976),  dim3(256), 0, stream>>>(x, w, xsT, xsTh, xsTl, Wth, Wtl, n2g, m2);
    k_g     <<<dim3(576),  dim3(256), 0, stream>>>(xsTh, xsTl, Wth, Wtl, G);
    k_selref<<<dim3(4096), dim3(256), 0, stream>>>(x, xsTh, xsTl, xsT, m2, n2g, idx);
    k_out   <<<dim3(1024), dim3(256), 0, stream>>>(G, idx, bias, out);
}